// Round 8
// baseline (793.849 us; speedup 1.0000x reference)
//
#include <hip/hip_runtime.h>
#include <stddef.h>
#include <stdint.h>

// Problem constants (AnatomicalTextEnhancer): B=16, R=29, D=512, N=20000, k=5
#define B_ 16
#define R_ 29
#define D_ 512
#define DF4 128                            // float4 per row
#define N_ 20000
#define K_ 5
#define TILE 256                           // rows per block (16 waves x 16)
#define NTIX ((N_ + TILE - 1) / TILE)      // 79 tiles per r
#define PCAND (NTIX * K_)                  // 395 candidates per (r,b)
#define NEG_MASK (-1.0e9f)
#define SENT (-3.0e38f)
#define IXMAX 0x7fffffff

// ---------------------------------------------------------------------------
// Kernel 1: L2-normalize queries, write transposed layout qn[r][b][d]
// ---------------------------------------------------------------------------
__global__ __launch_bounds__(64) void knorm_kernel(const float* __restrict__ q,
                                                   float* __restrict__ qn) {
    int pair = blockIdx.x;          // 0 .. B*R-1
    int b = pair / R_;
    int r = pair % R_;
    int lane = threadIdx.x;
    const float4* src = (const float4*)(q + ((size_t)(b * R_ + r)) * D_);
    float4 x0 = src[lane * 2];
    float4 x1 = src[lane * 2 + 1];
    float ss = x0.x * x0.x + x0.y * x0.y + x0.z * x0.z + x0.w * x0.w +
               x1.x * x1.x + x1.y * x1.y + x1.z * x1.z + x1.w * x1.w;
#pragma unroll
    for (int off = 32; off; off >>= 1) ss += __shfl_xor(ss, off);
    float inv = 1.0f / fmaxf(sqrtf(ss), 1e-12f);
    float4 y0, y1;
    y0.x = x0.x * inv; y0.y = x0.y * inv; y0.z = x0.z * inv; y0.w = x0.w * inv;
    y1.x = x1.x * inv; y1.y = x1.y * inv; y1.z = x1.z * inv; y1.w = x1.w * inv;
    float4* dst = (float4*)(qn + ((size_t)(r * B_ + b)) * D_);
    dst[lane * 2] = y0;
    dst[lane * 2 + 1] = y1;
}

// ---------------------------------------------------------------------------
// Kernel 2: occupancy-first variant of round-7. 1024 threads (16 waves),
// TILE=256 rows, M=2 rows/lane, 8-lane d-split (full 128B line per 8-row
// load, every requested line fully consumed by its own instruction).
// __launch_bounds__(1024,8) caps VGPR at 64 -> 8 waves/SIMD, 32 waves/CU
// (2 blocks/CU x 32KB LDS). q panel in LDS, broadcast b128 reads (one addr
// reg + immediate offsets). After compute: block-level top-5 merge in LDS
// (reusing the q panel), so only 5 candidates per (block, b) go to ktop.
// ---------------------------------------------------------------------------
__global__ __launch_bounds__(1024, 8) void ksim_kernel(const float* __restrict__ kb,
                                                       const float* __restrict__ qn,
                                                       const int* __restrict__ qid,
                                                       const int* __restrict__ kbid,
                                                       float* __restrict__ pvals,
                                                       int* __restrict__ pidx) {
    __shared__ float4 qs[B_ * DF4];       // 32 KB q panel (reused for merge)
    const int r = blockIdx.y;
    const int n0 = blockIdx.x * TILE;
    const int tid = threadIdx.x;

    // stage q panel once (coalesced), single barrier
    {
        const float4* src = (const float4*)(qn + (size_t)r * B_ * D_);
#pragma unroll
        for (int i = 0; i < 8; ++i) qs[tid + 1024 * i] = src[tid + 1024 * i];
    }
    __syncthreads();

    const int w = tid >> 6;               // wave 0..15 (owns 16 rows)
    const int lane = tid & 63;
    const int g = lane >> 3;              // row group 0..7
    const int s = lane & 7;               // d-split 0..7

    const char* kbb = (const char*)(kb + (size_t)r * N_ * D_);
    int rowi[2];
    unsigned off[2];
#pragma unroll
    for (int m = 0; m < 2; ++m) {
        rowi[m] = n0 + w * 16 + g + m * 8;
        int rc = rowi[m] < N_ ? rowi[m] : N_ - 1;   // clamp tail (masked later)
        off[m] = ((unsigned)rc * D_ + s * 4) * 4u;
    }

    float acc[2][B_];
    float nrm[2];
#pragma unroll
    for (int m = 0; m < 2; ++m) {
        nrm[m] = 0.0f;
#pragma unroll
        for (int b = 0; b < B_; ++b) acc[m][b] = 0.0f;
    }

    // main loop: p = 0..15; lane's chunk = float4 #(8p + s) of each row
#pragma unroll 4
    for (int p = 0; p < 16; ++p) {
        float4 kv0 = *(const float4*)(kbb + off[0] + (unsigned)(p * 128));
        float4 kv1 = *(const float4*)(kbb + off[1] + (unsigned)(p * 128));
        nrm[0] += kv0.x * kv0.x + kv0.y * kv0.y + kv0.z * kv0.z + kv0.w * kv0.w;
        nrm[1] += kv1.x * kv1.x + kv1.y * kv1.y + kv1.z * kv1.z + kv1.w * kv1.w;
#pragma unroll
        for (int b = 0; b < B_; ++b) {
            const float4 qv = qs[b * DF4 + p * 8 + s];   // bcast, 1 addr + imm
            acc[0][b] += kv0.x * qv.x + kv0.y * qv.y + kv0.z * qv.z + kv0.w * qv.w;
            acc[1][b] += kv1.x * qv.x + kv1.y * qv.y + kv1.z * qv.z + kv1.w * qv.w;
        }
    }

    // reduce partials over the 8 s-lanes (all lanes end with totals)
#pragma unroll
    for (int m = 0; m < 2; ++m) {
        nrm[m] += __shfl_xor(nrm[m], 1);
        nrm[m] += __shfl_xor(nrm[m], 2);
        nrm[m] += __shfl_xor(nrm[m], 4);
#pragma unroll
        for (int b = 0; b < B_; ++b) {
            acc[m][b] += __shfl_xor(acc[m][b], 1);
            acc[m][b] += __shfl_xor(acc[m][b], 2);
            acc[m][b] += __shfl_xor(acc[m][b], 4);
        }
    }

    float rinv[2];
    int myid[2];
#pragma unroll
    for (int m = 0; m < 2; ++m) {
        rinv[m] = 1.0f / fmaxf(sqrtf(nrm[m]), 1e-12f);
        myid[m] = (rowi[m] < N_) ? kbid[(size_t)r * N_ + rowi[m]] : -1;
    }

    __syncthreads();   // all waves done reading qs; reuse it as merge buffer
    float* vbuf = (float*)qs;                 // [16 b][16 w][5]
    int* ibuf = (int*)qs + B_ * 16 * K_;      // [16 b][16 w][5]

    // per-wave top-5 per b over its 16 rows (values 8-fold s-replicated;
    // identical copies keep argmax + removal consistent), written to LDS
    for (int b = 0; b < B_; ++b) {
        const int qb = qid[b];                // uniform -> scalar load
        float v[2];
#pragma unroll
        for (int m = 0; m < 2; ++m) {
            float sv = acc[m][b] * rinv[m];
            if (myid[m] == qb) sv = NEG_MASK;
            if (rowi[m] >= N_) sv = SENT;
            v[m] = sv;
        }
        for (int k = 0; k < K_; ++k) {
            float bv = v[0];
            int bx = rowi[0];
            if (v[1] > bv || (v[1] == bv && rowi[1] < bx)) { bv = v[1]; bx = rowi[1]; }
#pragma unroll
            for (int off2 = 8; off2 < 64; off2 <<= 1) {
                float ov = __shfl_xor(bv, off2);
                int ox = __shfl_xor(bx, off2);
                if (ov > bv || (ov == bv && ox < bx)) { bv = ov; bx = ox; }
            }
            if (lane == 0) {
                vbuf[(b * 16 + w) * K_ + k] = bv;
                ibuf[(b * 16 + w) * K_ + k] = bx;
            }
#pragma unroll
            for (int m = 0; m < 2; ++m)
                if (rowi[m] == bx) v[m] = SENT;   // remove winner (all copies)
        }
    }
    __syncthreads();

    // block-level merge: group w handles b = w; 80 candidates -> top-5
    {
        const int b = w;
        float v0 = SENT, v1 = SENT;
        int i0 = IXMAX, i1 = IXMAX;
        if (lane < 80) { v0 = vbuf[b * 80 + lane]; i0 = ibuf[b * 80 + lane]; }
        if (lane < 16) { v1 = vbuf[b * 80 + 64 + lane]; i1 = ibuf[b * 80 + 64 + lane]; }
        for (int k = 0; k < K_; ++k) {
            float bv = v0;
            int bx = i0;
            if (v1 > bv || (v1 == bv && i1 < bx)) { bv = v1; bx = i1; }
#pragma unroll
            for (int off2 = 1; off2 < 64; off2 <<= 1) {
                float ov = __shfl_xor(bv, off2);
                int ox = __shfl_xor(bx, off2);
                if (ov > bv || (ov == bv && ox < bx)) { bv = ov; bx = ox; }
            }
            if (lane == 0) {
                size_t o = (((size_t)r * B_ + b) * NTIX + blockIdx.x) * K_ + k;
                pvals[o] = bv;
                pidx[o] = bx;
            }
            if (i0 == bx) v0 = SENT;
            if (i1 == bx) v1 = SENT;
        }
    }
}

// ---------------------------------------------------------------------------
// Kernel 3: reduce 395 candidates per (b,r) to final top-5.
// Per-lane running sorted top-5 + 5 shuffle-argmax extractions.
// d_out layout (all float32): scores[B][R] | vals[B][R][5] | idx[B][R][5]
// ---------------------------------------------------------------------------
__global__ __launch_bounds__(64) void ktop_kernel(const float* __restrict__ pvals,
                                                  const int* __restrict__ pidx,
                                                  float* __restrict__ out) {
    int pair = blockIdx.x;      // 0 .. B*R-1
    int b = pair / R_;
    int r = pair % R_;
    int lane = threadIdx.x;
    const float* pv = pvals + ((size_t)r * B_ + b) * PCAND;
    const int* px = pidx + ((size_t)r * B_ + b) * PCAND;

    float tv[5];
    int tx[5];
#pragma unroll
    for (int t = 0; t < 5; ++t) { tv[t] = SENT; tx[t] = IXMAX; }

    for (int j = 0; j < (PCAND + 63) / 64; ++j) {
        int c = lane + 64 * j;
        if (c < PCAND) {
            float v = pv[c];
            int ix = px[c];
            if (v > tv[4] || (v == tv[4] && ix < tx[4])) {
                tv[4] = v; tx[4] = ix;
#pragma unroll
                for (int t = 4; t > 0; --t)
                    if (tv[t] > tv[t - 1] ||
                        (tv[t] == tv[t - 1] && tx[t] < tx[t - 1])) {
                        float fv = tv[t]; tv[t] = tv[t - 1]; tv[t - 1] = fv;
                        int fx = tx[t]; tx[t] = tx[t - 1]; tx[t - 1] = fx;
                    }
            }
        }
    }

#pragma unroll
    for (int k = 0; k < K_; ++k) {
        float bv = tv[0];
        int bx = tx[0];
#pragma unroll
        for (int off = 32; off; off >>= 1) {
            float ov = __shfl_xor(bv, off);
            int ox = __shfl_xor(bx, off);
            if (ov > bv || (ov == bv && ox < bx)) { bv = ov; bx = ox; }
        }
        if (lane == 0) {
            int p = b * R_ + r;
            if (k == 0) out[p] = bv;                       // similarity_scores
            out[B_ * R_ + (size_t)p * K_ + k] = bv;        // top_vals
            out[B_ * R_ + (size_t)B_ * R_ * K_ + (size_t)p * K_ + k] = (float)bx; // top_idx
        }
        // remove winner from this lane's sorted list (forward shift)
        bool f0 = (tx[0] == bx);
        bool f1 = f0 || (tx[1] == bx);
        bool f2 = f1 || (tx[2] == bx);
        bool f3 = f2 || (tx[3] == bx);
        bool f4 = f3 || (tx[4] == bx);
        if (f0) { tv[0] = tv[1]; tx[0] = tx[1]; }
        if (f1) { tv[1] = tv[2]; tx[1] = tx[2]; }
        if (f2) { tv[2] = tv[3]; tx[2] = tx[3]; }
        if (f3) { tv[3] = tv[4]; tx[3] = tx[4]; }
        if (f4) { tv[4] = SENT; tx[4] = IXMAX; }
    }
}

// ---------------------------------------------------------------------------
extern "C" void kernel_launch(void* const* d_in, const int* in_sizes, int n_in,
                              void* d_out, int out_size, void* d_ws, size_t ws_size,
                              hipStream_t stream) {
    const float* q    = (const float*)d_in[0];   // [B,R,D] fp32
    const float* kb   = (const float*)d_in[1];   // [R,N,D] fp32
    const int*   qid  = (const int*)d_in[2];     // [B]
    const int*   kbid = (const int*)d_in[3];     // [R,N]
    float* out = (float*)d_out;

    float* qn    = (float*)d_ws;                             // R*B*D floats
    float* pvals = qn + (size_t)R_ * B_ * D_;                // R*B*PCAND floats
    int*   pidx  = (int*)(pvals + (size_t)R_ * B_ * PCAND);

    knorm_kernel<<<B_ * R_, 64, 0, stream>>>(q, qn);
    dim3 g2(NTIX, R_);
    ksim_kernel<<<g2, 1024, 0, stream>>>(kb, qn, qid, kbid, pvals, pidx);
    ktop_kernel<<<B_ * R_, 64, 0, stream>>>(pvals, pidx, out);
}